// Round 13
// baseline (179.427 us; speedup 1.0000x reference)
//
#include <hip/hip_runtime.h>
#include <cmath>

typedef unsigned short u16;
typedef __bf16 bf16x8 __attribute__((ext_vector_type(8)));
typedef float f32x4 __attribute__((ext_vector_type(4)));

__device__ __forceinline__ u16 f2bf(float f) {
  unsigned u = __float_as_uint(f);
  u += 0x7fffu + ((u >> 16) & 1u);
  return (u16)(u >> 16);
}
__device__ __forceinline__ float bf2f(u16 h) {
  return __uint_as_float(((unsigned)h) << 16);
}
__device__ __forceinline__ f32x4 mfma_bf16(bf16x8 a, bf16x8 b, f32x4 c) {
  return __builtin_amdgcn_mfma_f32_16x16x32_bf16(a, b, c, 0, 0, 0);
}
__device__ __forceinline__ float gelu_exact(float x) {
  return 0.5f * x * (1.0f + erff(x * 0.70710678118654752440f));
}

// B=16, C=128, H=64, W=64, HW=4096, NPOS=65536
// LDS A-tile: [4*66 rows][136 u16] — 272B row stride (128ch + 8 pad).
#define ROWB 272

// ---------------- merged pack: X (NCHW f32 -> NHWC bf16) + weights ----------
__global__ __launch_bounds__(256) void pack_xw(
    const float* __restrict__ Fin, u16* __restrict__ X,
    const float* __restrict__ w0, const float* __restrict__ w1,
    const float* __restrict__ w2, const float* __restrict__ w3,
    const float* __restrict__ w4, u16* __restrict__ Wpk) {
  __shared__ float T[64 * 129];
  const int tid = threadIdx.x;
  if (blockIdx.x < 1024) {
    const int b = blockIdx.x >> 6, y = blockIdx.x & 63;
#pragma unroll
    for (int i = 0; i < 32; ++i) {
      int idx = tid + i * 256;
      int c = idx >> 6, x = idx & 63;
      T[x * 129 + c] = Fin[(size_t)(b * 128 + c) * 4096 + y * 64 + x];
    }
    __syncthreads();
#pragma unroll
    for (int i = 0; i < 4; ++i) {
      int chunk = tid + i * 256;
      int x = chunk >> 4;
      int c0 = (chunk & 15) * 8;
      u16 tmp[8];
#pragma unroll
      for (int e = 0; e < 8; ++e) tmp[e] = f2bf(T[x * 129 + c0 + e]);
      *reinterpret_cast<uint4*>(X + ((size_t)((b * 64 + y) * 64 + x) * 128 + c0)) =
          *reinterpret_cast<const uint4*>(tmp);
    }
  } else {
    int gid = (blockIdx.x - 1024) * 256 + tid;  // 92160 total
    int lane = gid & 63;
    int nblk = (gid >> 6) & 7;
    int step = (gid >> 9) % 36;
    int conv = gid / (512 * 36);
    if (conv >= 5) return;
    const float* w = conv == 0 ? w0 : conv == 1 ? w1 : conv == 2 ? w2 : conv == 3 ? w3 : w4;
    int tap = step >> 2, cc = step & 3;
    int dy = tap / 3, dx = tap % 3;
    int co = nblk * 16 + (lane & 15);
    int ci0 = cc * 32 + (lane >> 4) * 8;
    u16 tmp[8];
#pragma unroll
    for (int e = 0; e < 8; ++e)
      tmp[e] = f2bf(w[((size_t)(co * 128 + ci0 + e) * 3 + dy) * 3 + dx]);
    size_t off = ((size_t)conv * 36 * 8 * 64 + (size_t)((step * 8 + nblk) * 64 + lane)) * 8;
    *reinterpret_cast<uint4*>(Wpk + off) = *reinterpret_cast<const uint4*>(tmp);
  }
}

// ======== staging (512 threads): rows y0-1..y0+2, x-halo, 272B stride ======
__device__ __forceinline__ void stage_tile(const u16* __restrict__ Xin, char* Xsb,
                                           int tid, int b, int y0) {
#pragma unroll
  for (int i = 0; i < 8; ++i) {
    int j = tid + i * 512;
    int row = j >> 4;
    int c16 = j & 15;
    int ys = row >> 6, x = row & 63;
    int ysrc = y0 - 1 + ys;
    uint4 val = make_uint4(0u, 0u, 0u, 0u);
    if ((unsigned)ysrc < 64u)
      val = *reinterpret_cast<const uint4*>(
          Xin + ((size_t)((b * 64 + ysrc) * 64 + x) * 128 + c16 * 8));
    *reinterpret_cast<uint4*>(Xsb + (ys * 66 + x + 1) * ROWB + c16 * 16) = val;
  }
  if (tid < 128) {
    int j = 4096 + tid;
    int row = j >> 4;
    int c16 = j & 15;
    int ys = row >> 6, x = row & 63;
    int ysrc = y0 - 1 + ys;
    uint4 val = make_uint4(0u, 0u, 0u, 0u);
    if ((unsigned)ysrc < 64u)
      val = *reinterpret_cast<const uint4*>(
          Xin + ((size_t)((b * 64 + ysrc) * 64 + x) * 128 + c16 * 8));
    *reinterpret_cast<uint4*>(Xsb + (ys * 66 + x + 1) * ROWB + c16 * 16) = val;
  } else if (tid < 256) {
    int t = tid - 128;
    int ys = t >> 5, side = (t >> 4) & 1, c16 = t & 15;
    int xs = side ? 65 : 0;
    *reinterpret_cast<uint4*>(Xsb + (ys * 66 + xs) * ROWB + c16 * 16) =
        make_uint4(0u, 0u, 0u, 0u);
  }
}

// ---------------- fused QKV conv3x3, 512 threads / 8 waves ------------------
// BM=128, BN=64 (nh). Wave (wm=wv>>1 in 0..3: M=32; wn=wv&1: N=32).
__global__ __launch_bounds__(512, 4) void conv_qkv(
    const u16* __restrict__ Xin, const u16* __restrict__ Wp,
    const float* __restrict__ qb, const float* __restrict__ kb,
    const float* __restrict__ vb, u16* __restrict__ QP,
    u16* __restrict__ KP, u16* __restrict__ Vout) {
  __shared__ alignas(16) char Xsb[4 * 66 * ROWB];  // 71808 B
  const int tid = threadIdx.x;
  const int lane = tid & 63;
  const int wv = tid >> 6;
  const int wm = wv >> 1, wn = wv & 1;
  int mt = blockIdx.x;
  mt = (mt & 7) * 128 + (mt >> 3);  // 1024 blocks, bijective XCD swizzle
  const int b = mt >> 6;
  const int r = mt & 63;
  const int yp = r >> 1;      // y-pair 0..31
  const int nh = r & 1;       // N half
  const int y0 = yp * 2;

  stage_tile(Xin, Xsb, tid, b, y0);
  __syncthreads();

  f32x4 acc[3][2][2];
#pragma unroll
  for (int c = 0; c < 3; ++c)
#pragma unroll
    for (int i = 0; i < 2; ++i)
#pragma unroll
      for (int j = 0; j < 2; ++j) acc[c][i][j] = f32x4{0.f, 0.f, 0.f, 0.f};

  const int lm = lane & 15, lq = lane >> 4;
  const int pos0 = wm * 32 + lm, pos1 = pos0 + 16;
  const int base0 = ((pos0 >> 6) * 66 + (pos0 & 63)) * ROWB + lq * 16;
  const int base1 = ((pos1 >> 6) * 66 + (pos1 & 63)) * ROWB + lq * 16;
  const u16* wb = Wp + (size_t)(((nh * 4 + wn * 2) * 64) + lane) * 8;

  auto loada = [&](bf16x8 (&d)[2], int s) {
    int tap = s >> 2, cc = s & 3;
    int dy = (tap * 11) >> 5;
    int dx = tap - dy * 3;
    int off = (dy * 66 + dx) * ROWB + cc * 64;
    d[0] = *reinterpret_cast<const bf16x8*>(Xsb + base0 + off);
    d[1] = *reinterpret_cast<const bf16x8*>(Xsb + base1 + off);
  };
  auto loadb = [&](bf16x8 (&d)[6], int s) {
#pragma unroll
    for (int cv = 0; cv < 3; ++cv)
#pragma unroll
      for (int j = 0; j < 2; ++j)
        d[cv * 2 + j] = *reinterpret_cast<const bf16x8*>(
            wb + (size_t)cv * 147456 + (size_t)s * 4096 + j * 512);
  };
  auto step = [&](bf16x8 (&a)[2], bf16x8 (&bm)[6]) {
#pragma unroll
    for (int cv = 0; cv < 3; ++cv)
#pragma unroll
      for (int i = 0; i < 2; ++i)
#pragma unroll
        for (int j = 0; j < 2; ++j)
          acc[cv][i][j] = mfma_bf16(a[i], bm[cv * 2 + j], acc[cv][i][j]);
  };

  bf16x8 a0[2], a1[2], b0[6], b1[6];
  loada(a0, 0);
  loadb(b0, 0);
#pragma unroll 1
  for (int s = 0; s < 36; s += 2) {
    loada(a1, s + 1);
    loadb(b1, s + 1);
    step(a0, b0);
    if (s + 2 < 36) {
      loada(a0, s + 2);
      loadb(b0, s + 2);
    }
    step(a1, b1);
  }

  __syncthreads();  // Xs dead; reuse for epilogues

  // ---- Q, K: fragment-packed epilogue ----
  u16* T = reinterpret_cast<u16*>(Xsb);  // [64][136]
#pragma unroll
  for (int cv = 0; cv < 2; ++cv) {
    const float* bias = cv == 0 ? qb : kb;
    u16* OutB = cv == 0 ? QP : KP;
#pragma unroll
    for (int i = 0; i < 2; ++i)
#pragma unroll
      for (int j = 0; j < 2; ++j) {
        int nloc = wn * 32 + j * 16 + lm;
        float bs = bias[nh * 64 + nloc];
#pragma unroll
        for (int rr = 0; rr < 4; ++rr) {
          int m = wm * 32 + i * 16 + lq * 4 + rr;
          T[nloc * 136 + m] = f2bf(acc[cv][i][j][rr] + bs);
        }
      }
    __syncthreads();
#pragma unroll
    for (int it = 0; it < 2; ++it) {
      int item = tid + it * 512;  // 0..1023
      int l = item & 63, cbl = (item >> 6) & 3, ksl = item >> 8;
      int c = cbl * 16 + (l & 15);
      int mloc = ksl * 32 + (l >> 4) * 8;
      int ks = yp * 4 + ksl, cb = nh * 4 + cbl;
      *reinterpret_cast<uint4*>(
          OutB + (size_t)(((b * 128 + ks) * 8 + cb) * 64 + l) * 8) =
          *reinterpret_cast<const uint4*>(T + c * 136 + mloc);
    }
    __syncthreads();
  }

  // ---- V: natural [pos][ch] ----
  u16* Tv = reinterpret_cast<u16*>(Xsb);  // [128][72]
#pragma unroll
  for (int i = 0; i < 2; ++i)
#pragma unroll
    for (int j = 0; j < 2; ++j) {
      int nloc = wn * 32 + j * 16 + lm;
      float bs = vb[nh * 64 + nloc];
#pragma unroll
      for (int rr = 0; rr < 4; ++rr) {
        int m = wm * 32 + i * 16 + lq * 4 + rr;
        Tv[m * 72 + nloc] = f2bf(acc[2][i][j][rr] + bs);
      }
    }
  __syncthreads();
#pragma unroll
  for (int it = 0; it < 2; ++it) {
    int item = tid + it * 512;  // 0..1023 uint4 chunks
    int rr = item >> 3, q = item & 7;
    *reinterpret_cast<uint4*>(
        Vout + ((size_t)((b * 32 + yp) * 128 + rr) * 128 + nh * 64 + q * 8)) =
        *reinterpret_cast<const uint4*>(Tv + rr * 72 + q * 8);
  }
}

// ---------------- FFN convs, 512 threads / 8 waves ----------------
// BM=128, BN=128. Wave (wm in 0..3: M=32; wn in 0..1: N=64).
// MODE 1: f1' (per-batch folded weights, gelu -> natural bf16 Hid)
// MODE 3: f2' (f32 NCHW out + inline V@M residual)
template <int MODE>
__global__ __launch_bounds__(512, 4) void conv_gemm(
    const u16* __restrict__ Xin, const u16* __restrict__ Wp,
    const float* __restrict__ bias, u16* __restrict__ OutB,
    float* __restrict__ OutF, const u16* __restrict__ Vin,
    const u16* __restrict__ Mpk) {
  __shared__ alignas(16) char Xsb[4 * 66 * ROWB];  // 71808 B
  const int tid = threadIdx.x;
  const int lane = tid & 63;
  const int wv = tid >> 6;
  const int wm = wv >> 1, wn = wv & 1;
  int mt = blockIdx.x;
  mt = (mt & 7) * 64 + (mt >> 3);
  const int b = mt >> 5;
  const int y0 = (mt & 31) * 2;

  stage_tile(Xin, Xsb, tid, b, y0);
  __syncthreads();

  f32x4 acc[2][4];
#pragma unroll
  for (int i = 0; i < 2; ++i)
#pragma unroll
    for (int j = 0; j < 4; ++j) acc[i][j] = f32x4{0.f, 0.f, 0.f, 0.f};

  const int lm = lane & 15, lq = lane >> 4;
  const int pos0 = wm * 32 + lm, pos1 = pos0 + 16;
  const int base0 = ((pos0 >> 6) * 66 + (pos0 & 63)) * ROWB + lq * 16;
  const int base1 = ((pos1 >> 6) * 66 + (pos1 & 63)) * ROWB + lq * 16;
  const u16* wb = Wp + (MODE == 1 ? (size_t)b * 147456 : (size_t)0) +
                  (size_t)((wn * 4 * 64) + lane) * 8;

  auto loada = [&](bf16x8 (&d)[2], int s) {
    int tap = s >> 2, cc = s & 3;
    int dy = (tap * 11) >> 5;
    int dx = tap - dy * 3;
    int off = (dy * 66 + dx) * ROWB + cc * 64;
    d[0] = *reinterpret_cast<const bf16x8*>(Xsb + base0 + off);
    d[1] = *reinterpret_cast<const bf16x8*>(Xsb + base1 + off);
  };
  auto loadb = [&](bf16x8 (&d)[4], int s) {
#pragma unroll
    for (int j = 0; j < 4; ++j)
      d[j] = *reinterpret_cast<const bf16x8*>(wb + (size_t)s * 4096 + j * 512);
  };
  auto step = [&](bf16x8 (&a)[2], bf16x8 (&bm)[4]) {
#pragma unroll
    for (int i = 0; i < 2; ++i)
#pragma unroll
      for (int j = 0; j < 4; ++j) acc[i][j] = mfma_bf16(a[i], bm[j], acc[i][j]);
  };

  bf16x8 a0[2], a1[2], b0[4], b1[4];
  loada(a0, 0);
  loadb(b0, 0);
#pragma unroll 1
  for (int s = 0; s < 36; s += 2) {
    loada(a1, s + 1);
    loadb(b1, s + 1);
    step(a0, b0);
    if (s + 2 < 36) {
      loada(a0, s + 2);
      loadb(b0, s + 2);
    }
    step(a1, b1);
  }

  __syncthreads();

  if (MODE == 1) {
    u16* T = reinterpret_cast<u16*>(Xsb);  // [128][136]
#pragma unroll
    for (int i = 0; i < 2; ++i)
#pragma unroll
      for (int j = 0; j < 4; ++j) {
        int n = wn * 64 + j * 16 + lm;
        float bs = bias[n];
#pragma unroll
        for (int r = 0; r < 4; ++r) {
          int m = wm * 32 + i * 16 + lq * 4 + r;
          T[m * 136 + n] = f2bf(gelu_exact(acc[i][j][r] + bs));
        }
      }
    __syncthreads();
#pragma unroll
    for (int it = 0; it < 4; ++it) {
      int item = tid + it * 512;  // 0..2047 uint4
      int rr = item >> 4, hf = item & 15;
      *reinterpret_cast<uint4*>(OutB + ((size_t)(mt * 128 + rr) * 128 + hf * 8)) =
          *reinterpret_cast<const uint4*>(T + rr * 136 + hf * 8);
    }
  } else {
    // inline residual: R = V @ M for this tile (f32, K=128)
    f32x4 accR[2][4];
#pragma unroll
    for (int i = 0; i < 2; ++i)
#pragma unroll
      for (int j = 0; j < 4; ++j) accR[i][j] = f32x4{0.f, 0.f, 0.f, 0.f};
#pragma unroll
    for (int cc = 0; cc < 4; ++cc) {
      int k0 = cc * 32 + lq * 8;
      bf16x8 af[2], bfr[4];
#pragma unroll
      for (int i = 0; i < 2; ++i)
        af[i] = *reinterpret_cast<const bf16x8*>(
            Vin + (size_t)(mt * 128 + wm * 32 + i * 16 + lm) * 128 + k0);
#pragma unroll
      for (int j = 0; j < 4; ++j)
        bfr[j] = *reinterpret_cast<const bf16x8*>(
            Mpk + (size_t)b * 16384 + (size_t)((cc * 8 + wn * 4 + j) * 64 + lane) * 8);
#pragma unroll
      for (int i = 0; i < 2; ++i)
#pragma unroll
        for (int j = 0; j < 4; ++j) accR[i][j] = mfma_bf16(af[i], bfr[j], accR[i][j]);
    }

    float* T = reinterpret_cast<float*>(Xsb);  // [128][132] f32 = 67584 B
#pragma unroll
    for (int i = 0; i < 2; ++i)
#pragma unroll
      for (int j = 0; j < 4; ++j) {
        int n = wn * 64 + j * 16 + lm;
        float bs = bias[n];
#pragma unroll
        for (int r = 0; r < 4; ++r) {
          int m = wm * 32 + i * 16 + lq * 4 + r;
          T[n * 132 + m] = acc[i][j][r] + bs + accR[i][j][r];
        }
      }
    __syncthreads();
#pragma unroll
    for (int it = 0; it < 8; ++it) {
      int item = tid + it * 512;  // 0..4095 float4
      int n2 = item >> 5, seg = item & 31;
      *reinterpret_cast<float4*>(
          OutF + ((size_t)(b * 128 + n2) * 4096 + (mt & 31) * 128 + seg * 4)) =
          *reinterpret_cast<const float4*>(T + n2 * 132 + seg * 4);
    }
  }
}

// ---------------- S = K^T Q, split-K=8 -> f32 partials ----------------
__global__ __launch_bounds__(256, 2) void attn_s(const u16* __restrict__ QP,
                                                 const u16* __restrict__ KP,
                                                 float* __restrict__ SP) {
  const int tid = threadIdx.x;
  const int lane = tid & 63;
  const int wv = tid >> 6, wm = wv >> 1, wn = wv & 1;
  const int lm = lane & 15, lq = lane >> 4;
  int mt = blockIdx.x;
  mt = (mt & 7) * 16 + (mt >> 3);  // 128 blocks, bijective
  const int b = mt >> 3, sp = mt & 7;

  f32x4 acc[4][4];
#pragma unroll
  for (int i = 0; i < 4; ++i)
#pragma unroll
    for (int j = 0; j < 4; ++j) acc[i][j] = f32x4{0.f, 0.f, 0.f, 0.f};

#pragma unroll
  for (int ksl = 0; ksl < 16; ++ksl) {
    const int ks = sp * 16 + ksl;
    bf16x8 af[4], bfr[4];
#pragma unroll
    for (int i = 0; i < 4; ++i)
      af[i] = *reinterpret_cast<const bf16x8*>(
          KP + (size_t)(((b * 128 + ks) * 8 + wm * 4 + i) * 64 + lane) * 8);
#pragma unroll
    for (int j = 0; j < 4; ++j)
      bfr[j] = *reinterpret_cast<const bf16x8*>(
          QP + (size_t)(((b * 128 + ks) * 8 + wn * 4 + j) * 64 + lane) * 8);
#pragma unroll
    for (int i = 0; i < 4; ++i)
#pragma unroll
      for (int j = 0; j < 4; ++j) acc[i][j] = mfma_bf16(af[i], bfr[j], acc[i][j]);
  }

  float* out = SP + (size_t)(b * 8 + sp) * 16384;
#pragma unroll
  for (int i = 0; i < 4; ++i)
#pragma unroll
    for (int j = 0; j < 4; ++j)
#pragma unroll
      for (int r = 0; r < 4; ++r)
        out[(wm * 64 + i * 16 + lq * 4 + r) * 128 + wn * 64 + j * 16 + lm] =
            acc[i][j][r];
}

// ---- fused: reduce partials + softmax + M=Pspe@A + pack M both ways -------
__global__ __launch_bounds__(256, 1) void attn_rm(const float* __restrict__ SP,
                                                  const float* __restrict__ Pspe,
                                                  u16* __restrict__ Mpack,
                                                  u16* __restrict__ Mpack2) {
  __shared__ float Sf[128 * 129];  // 66048 B
  __shared__ u16 AT[128 * 136];    // 34816 B
  const int b = blockIdx.x;
  const int tid = threadIdx.x;
  const int lane = tid & 63;
  const int wv = tid >> 6, wm = wv >> 1, wn = wv & 1;
  const int lm = lane & 15, lq = lane >> 4;

#pragma unroll
  for (int it = 0; it < 64; ++it) {
    int id = it * 256 + tid;
    int rl = id >> 7, d = id & 127;
    const float* p = SP + (size_t)b * 8 * 16384 + (size_t)rl * 128 + d;
    float s = 0.f;
#pragma unroll
    for (int sp = 0; sp < 8; ++sp) s += p[(size_t)sp * 16384];
    Sf[rl * 129 + d] = s * 0.015625f;  // /sqrt(4096)
  }
  __syncthreads();

  {
    int c = tid >> 1, hf = tid & 1;
    float* row = Sf + c * 129 + hf * 64;
    float mx = -3.4e38f;
#pragma unroll
    for (int k = 0; k < 64; ++k) mx = fmaxf(mx, row[k]);
    mx = fmaxf(mx, __shfl_xor(mx, 1));
    float s = 0.f;
#pragma unroll
    for (int k = 0; k < 64; ++k) {
      float e = __expf(row[k] - mx);
      row[k] = e;
      s += e;
    }
    s += __shfl_xor(s, 1);
    float inv = 1.0f / s;
#pragma unroll
    for (int k = 0; k < 64; ++k) AT[(hf * 64 + k) * 136 + c] = f2bf(row[k] * inv);
  }
  __syncthreads();

  // M = Pspe @ A
  f32x4 acc2[4][4];
#pragma unroll
  for (int i = 0; i < 4; ++i)
#pragma unroll
    for (int j = 0; j < 4; ++j) acc2[i][j] = f32x4{0.f, 0.f, 0.f, 0.f};
  const float* P = Pspe + (size_t)b * 128 * 128;
#pragma unroll
  for (int cc = 0; cc < 4; ++cc) {
    int e0 = cc * 32 + lq * 8;
    bf16x8 af[4], bfr[4];
#pragma unroll
    for (int i = 0; i < 4; ++i) {
      const float* p = P + (size_t)(wm * 64 + i * 16 + lm) * 128 + e0;
      union { u16 u[8]; bf16x8 v; } cvt;
#pragma unroll
      for (int e = 0; e < 8; ++e) cvt.u[e] = f2bf(p[e]);
      af[i] = cvt.v;
    }
#pragma unroll
    for (int j = 0; j < 4; ++j)
      bfr[j] = *reinterpret_cast<const bf16x8*>(AT + (wn * 64 + j * 16 + lm) * 136 + e0);
#pragma unroll
    for (int i = 0; i < 4; ++i)
#pragma unroll
      for (int j = 0; j < 4; ++j) acc2[i][j] = mfma_bf16(af[i], bfr[j], acc2[i][j]);
  }

  // M^T [d][c] into Ml (aliases Sf)
  u16* Ml = reinterpret_cast<u16*>(Sf);  // [128][136]
#pragma unroll
  for (int i = 0; i < 4; ++i)
#pragma unroll
    for (int j = 0; j < 4; ++j)
#pragma unroll
      for (int r = 0; r < 4; ++r)
        Ml[(wn * 64 + j * 16 + lm) * 136 + (wm * 64 + i * 16 + lq * 4 + r)] =
            f2bf(acc2[i][j][r]);
  __syncthreads();

  // Mpack: fragments with (frag-row = d, k = c)  [for f2' V@M residual]
#pragma unroll
  for (int it = 0; it < 8; ++it) {
    int item = tid + it * 256;
    int l2 = item & 63, nb = (item >> 6) & 7, cc2 = item >> 9;
    int d = nb * 16 + (l2 & 15), c0 = cc2 * 32 + (l2 >> 4) * 8;
    *reinterpret_cast<uint4*>(Mpack + (size_t)b * 16384 + (size_t)item * 8) =
        *reinterpret_cast<const uint4*>(Ml + d * 136 + c0);
  }
  // Mpack2: fragments with (frag-row = c, k = d)  [for wfold1]
#pragma unroll
  for (int it = 0; it < 8; ++it) {
    int item = tid + it * 256;
    int l2 = item & 63, nb = (item >> 6) & 7, cc2 = item >> 9;
    int c = nb * 16 + (l2 & 15), d0 = cc2 * 32 + (l2 >> 4) * 8;
    u16 tmp[8];
#pragma unroll
    for (int e = 0; e < 8; ++e) tmp[e] = Ml[(d0 + e) * 136 + c];
    *reinterpret_cast<uint4*>(Mpack2 + (size_t)b * 16384 + (size_t)item * 8) =
        *reinterpret_cast<const uint4*>(tmp);
  }
}

// ---- wfold1: W1'[co][c,tap] = sum_d W1[co][d,tap] * M[c][d] ---------------
__global__ __launch_bounds__(256, 2) void wfold1(const u16* __restrict__ W1pk,
                                                 const u16* __restrict__ Mpk2,
                                                 u16* __restrict__ Wf1) {
  __shared__ u16 T[128 * 136];
  const int tid = threadIdx.x;
  const int lane = tid & 63, wv = tid >> 6;
  const int wm = wv >> 1, wn = wv & 1;
  const int lm = lane & 15, lq = lane >> 4;
  const int b = blockIdx.x / 9, tap = blockIdx.x % 9;

  f32x4 acc[4][4];
#pragma unroll
  for (int i = 0; i < 4; ++i)
#pragma unroll
    for (int j = 0; j < 4; ++j) acc[i][j] = f32x4{0.f, 0.f, 0.f, 0.f};

#pragma unroll
  for (int cc = 0; cc < 4; ++cc) {
    bf16x8 af[4], bfr[4];
#pragma unroll
    for (int i = 0; i < 4; ++i)
      af[i] = *reinterpret_cast<const bf16x8*>(
          W1pk + (size_t)(((tap * 4 + cc) * 8 + wm * 4 + i) * 64 + lane) * 8);
#pragma unroll
    for (int j = 0; j < 4; ++j)
      bfr[j] = *reinterpret_cast<const bf16x8*>(
          Mpk2 + (size_t)b * 16384 + (size_t)((cc * 8 + wn * 4 + j) * 64 + lane) * 8);
#pragma unroll
    for (int i = 0; i < 4; ++i)
#pragma unroll
      for (int j = 0; j < 4; ++j) acc[i][j] = mfma_bf16(af[i], bfr[j], acc[i][j]);
  }

#pragma unroll
  for (int i = 0; i < 4; ++i)
#pragma unroll
    for (int j = 0; j < 4; ++j)
#pragma unroll
      for (int r = 0; r < 4; ++r)
        T[(wm * 64 + i * 16 + lq * 4 + r) * 136 + wn * 64 + j * 16 + lm] =
            f2bf(acc[i][j][r]);
  __syncthreads();

#pragma unroll
  for (int it = 0; it < 8; ++it) {
    int item = tid + it * 256;  // 0..2047
    int L = item & 63, nb = (item >> 6) & 7, cc2 = item >> 9;
    int co = nb * 16 + (L & 15);
    int c0 = cc2 * 32 + (L >> 4) * 8;
    *reinterpret_cast<uint4*>(
        Wf1 + (size_t)b * 147456 +
        ((size_t)(((tap * 4 + cc2) * 8 + nb) * 64 + L)) * 8) =
        *reinterpret_cast<const uint4*>(T + co * 136 + c0);
  }
}

extern "C" void kernel_launch(void* const* d_in, const int* in_sizes, int n_in,
                              void* d_out, int out_size, void* d_ws, size_t ws_size,
                              hipStream_t stream) {
  const float* F_in = (const float*)d_in[0];
  const float* Pspe = (const float*)d_in[1];
  const float* q_w = (const float*)d_in[2];
  const float* q_b = (const float*)d_in[3];
  const float* k_w = (const float*)d_in[4];
  const float* k_b = (const float*)d_in[5];
  const float* v_w = (const float*)d_in[6];
  const float* v_b = (const float*)d_in[7];
  const float* f1_w = (const float*)d_in[8];
  const float* f1_b = (const float*)d_in[9];
  const float* f2_w = (const float*)d_in[10];
  const float* f2_b = (const float*)d_in[11];
  float* out = (float*)d_out;

  char* ws = (char*)d_ws;
  const size_t SZ = 16777216;  // 65536*128*2 bytes
  u16* X = (u16*)(ws);                   // NHWC bf16 input; SP aliases later
  u16* QP = (u16*)(ws + SZ);             // packed Q; later Hid
  u16* KP = (u16*)(ws + 2 * SZ);         // packed K
  u16* V = (u16*)(ws + 3 * SZ);          // natural V (alive until f2')
  u16* Wpk = (u16*)(ws + 4 * SZ);                    // 1,474,560 B
  u16* Mpk = (u16*)(ws + 4 * SZ + 1474560);          // 524,288 B
  u16* Mpk2 = (u16*)(ws + 4 * SZ + 1998848);         // 524,288 B
  u16* Wf1 = (u16*)(ws + 4 * SZ + 2523136);          // 4,718,592 B -> ~74.4 MB
  float* SP = (float*)ws;                // 8.39 MB partials — aliases X (dead)
  u16* Hid = QP;                         // f1' output — aliases QP (dead)

  pack_xw<<<1384, 256, 0, stream>>>(F_in, X, q_w, k_w, v_w, f1_w, f2_w, Wpk);
  conv_qkv<<<1024, 512, 0, stream>>>(X, Wpk, q_b, k_b, v_b, QP, KP, V);
  attn_s<<<128, 256, 0, stream>>>(QP, KP, SP);
  attn_rm<<<16, 256, 0, stream>>>(SP, Pspe, Mpk, Mpk2);
  wfold1<<<144, 256, 0, stream>>>(Wpk + 3 * 147456, Mpk2, Wf1);
  conv_gemm<1><<<512, 512, 0, stream>>>(V, Wf1, f1_b, Hid, nullptr, nullptr,
                                        nullptr);
  conv_gemm<3><<<512, 512, 0, stream>>>(Hid, Wpk + 4 * 147456, f2_b, nullptr,
                                        out, V, Mpk);
}

// Round 14
// 170.550 us; speedup vs baseline: 1.0521x; 1.0521x over previous
//
#include <hip/hip_runtime.h>
#include <cmath>

typedef unsigned short u16;
typedef __bf16 bf16x8 __attribute__((ext_vector_type(8)));
typedef float f32x4 __attribute__((ext_vector_type(4)));

__device__ __forceinline__ u16 f2bf(float f) {
  unsigned u = __float_as_uint(f);
  u += 0x7fffu + ((u >> 16) & 1u);
  return (u16)(u >> 16);
}
__device__ __forceinline__ float bf2f(u16 h) {
  return __uint_as_float(((unsigned)h) << 16);
}
__device__ __forceinline__ f32x4 mfma_bf16(bf16x8 a, bf16x8 b, f32x4 c) {
  return __builtin_amdgcn_mfma_f32_16x16x32_bf16(a, b, c, 0, 0, 0);
}
__device__ __forceinline__ float gelu_exact(float x) {
  return 0.5f * x * (1.0f + erff(x * 0.70710678118654752440f));
}

// B=16, C=128, H=64, W=64, HW=4096, NPOS=65536
// LDS A-tile: [4*66 rows][136 u16] — 272B row stride (128ch + 8 pad).
#define ROWB 272

// ---------------- merged pack: X (NCHW f32 -> NHWC bf16) + weights ----------
__global__ __launch_bounds__(256) void pack_xw(
    const float* __restrict__ Fin, u16* __restrict__ X,
    const float* __restrict__ w0, const float* __restrict__ w1,
    const float* __restrict__ w2, const float* __restrict__ w3,
    const float* __restrict__ w4, u16* __restrict__ Wpk) {
  __shared__ float T[64 * 129];
  const int tid = threadIdx.x;
  if (blockIdx.x < 1024) {
    const int b = blockIdx.x >> 6, y = blockIdx.x & 63;
#pragma unroll
    for (int i = 0; i < 32; ++i) {
      int idx = tid + i * 256;
      int c = idx >> 6, x = idx & 63;
      T[x * 129 + c] = Fin[(size_t)(b * 128 + c) * 4096 + y * 64 + x];
    }
    __syncthreads();
#pragma unroll
    for (int i = 0; i < 4; ++i) {
      int chunk = tid + i * 256;
      int x = chunk >> 4;
      int c0 = (chunk & 15) * 8;
      u16 tmp[8];
#pragma unroll
      for (int e = 0; e < 8; ++e) tmp[e] = f2bf(T[x * 129 + c0 + e]);
      *reinterpret_cast<uint4*>(X + ((size_t)((b * 64 + y) * 64 + x) * 128 + c0)) =
          *reinterpret_cast<const uint4*>(tmp);
    }
  } else {
    int gid = (blockIdx.x - 1024) * 256 + tid;  // 92160 total
    int lane = gid & 63;
    int nblk = (gid >> 6) & 7;
    int step = (gid >> 9) % 36;
    int conv = gid / (512 * 36);
    if (conv >= 5) return;
    const float* w = conv == 0 ? w0 : conv == 1 ? w1 : conv == 2 ? w2 : conv == 3 ? w3 : w4;
    int tap = step >> 2, cc = step & 3;
    int dy = tap / 3, dx = tap % 3;
    int co = nblk * 16 + (lane & 15);
    int ci0 = cc * 32 + (lane >> 4) * 8;
    u16 tmp[8];
#pragma unroll
    for (int e = 0; e < 8; ++e)
      tmp[e] = f2bf(w[((size_t)(co * 128 + ci0 + e) * 3 + dy) * 3 + dx]);
    size_t off = ((size_t)conv * 36 * 8 * 64 + (size_t)((step * 8 + nblk) * 64 + lane)) * 8;
    *reinterpret_cast<uint4*>(Wpk + off) = *reinterpret_cast<const uint4*>(tmp);
  }
}

// ======== staging: rows y0-1..y0+2, x-halo, linear 272B-stride layout ======
__device__ __forceinline__ void stage_tile(const u16* __restrict__ Xin, char* Xsb,
                                           int tid, int b, int y0) {
#pragma unroll
  for (int i = 0; i < 16; ++i) {
    int j = tid + i * 256;
    int row = j >> 4;
    int c16 = j & 15;
    int ys = row >> 6, x = row & 63;
    int ysrc = y0 - 1 + ys;
    uint4 val = make_uint4(0u, 0u, 0u, 0u);
    if ((unsigned)ysrc < 64u)
      val = *reinterpret_cast<const uint4*>(
          Xin + ((size_t)((b * 64 + ysrc) * 64 + x) * 128 + c16 * 8));
    *reinterpret_cast<uint4*>(Xsb + (ys * 66 + x + 1) * ROWB + c16 * 16) = val;
  }
  if (tid < 128) {
    int ys = tid >> 5, side = (tid >> 4) & 1, c16 = tid & 15;
    int xs = side ? 65 : 0;
    *reinterpret_cast<uint4*>(Xsb + (ys * 66 + xs) * ROWB + c16 * 16) =
        make_uint4(0u, 0u, 0u, 0u);
  }
}

// ---------------- fused QKV conv3x3, M128xN64, 3-deep pipeline --------------
__global__ __launch_bounds__(256, 2) void conv_qkv(
    const u16* __restrict__ Xin, const u16* __restrict__ Wp,
    const float* __restrict__ qb, const float* __restrict__ kb,
    const float* __restrict__ vb, u16* __restrict__ QP,
    u16* __restrict__ KP, u16* __restrict__ Vout) {
  __shared__ alignas(16) char Xsb[4 * 66 * ROWB];  // 71808 B
  const int tid = threadIdx.x;
  const int lane = tid & 63;
  const int wv = tid >> 6;
  const int wm = wv >> 1, wn = wv & 1;
  int mt = blockIdx.x;
  mt = (mt & 7) * 128 + (mt >> 3);  // 1024 blocks, bijective XCD swizzle
  const int b = mt >> 6;
  const int r = mt & 63;
  const int yp = r >> 1;      // y-pair 0..31
  const int nh = r & 1;       // N half
  const int y0 = yp * 2;

  stage_tile(Xin, Xsb, tid, b, y0);
  __syncthreads();

  f32x4 acc[3][4][2];
#pragma unroll
  for (int c = 0; c < 3; ++c)
#pragma unroll
    for (int i = 0; i < 4; ++i)
#pragma unroll
      for (int j = 0; j < 2; ++j) acc[c][i][j] = f32x4{0.f, 0.f, 0.f, 0.f};

  const int lm = lane & 15, lq = lane >> 4;
  const int abase = lm * ROWB + lq * 16;
  const u16* wb = Wp + (size_t)(((nh * 4 + wn * 2) * 64) + lane) * 8;

  auto loada = [&](bf16x8 (&d)[4], int s) {
    int tap = s >> 2, cc = s & 3;
    int dy = (tap * 11) >> 5;
    int dx = tap - dy * 3;
    int roff = ((wm + dy) * 66 + dx) * ROWB + cc * 64 + abase;
#pragma unroll
    for (int i = 0; i < 4; ++i)
      d[i] = *reinterpret_cast<const bf16x8*>(Xsb + roff + i * (16 * ROWB));
  };
  auto loadb = [&](bf16x8 (&d)[6], int s) {
#pragma unroll
    for (int cv = 0; cv < 3; ++cv)
#pragma unroll
      for (int j = 0; j < 2; ++j)
        d[cv * 2 + j] = *reinterpret_cast<const bf16x8*>(
            wb + (size_t)cv * 147456 + (size_t)s * 4096 + j * 512);
  };
  auto step = [&](bf16x8 (&a)[4], bf16x8 (&bm)[6]) {
#pragma unroll
    for (int cv = 0; cv < 3; ++cv)
#pragma unroll
      for (int i = 0; i < 4; ++i)
#pragma unroll
        for (int j = 0; j < 2; ++j)
          acc[cv][i][j] = mfma_bf16(a[i], bm[cv * 2 + j], acc[cv][i][j]);
  };

  bf16x8 a0[4], a1[4], a2[4], b0[6], b1[6], b2[6];
  loada(a0, 0); loadb(b0, 0);
  loada(a1, 1); loadb(b1, 1);
  loada(a2, 2); loadb(b2, 2);
#pragma unroll 1
  for (int s = 0; s < 36; s += 3) {
    step(a0, b0);
    if (s + 3 < 36) { loada(a0, s + 3); loadb(b0, s + 3); }
    step(a1, b1);
    if (s + 4 < 36) { loada(a1, s + 4); loadb(b1, s + 4); }
    step(a2, b2);
    if (s + 5 < 36) { loada(a2, s + 5); loadb(b2, s + 5); }
  }

  __syncthreads();  // Xs dead; reuse for epilogues

  // ---- Q, K: fragment-packed epilogue ----
  u16* T = reinterpret_cast<u16*>(Xsb);  // [64][136]
#pragma unroll
  for (int cv = 0; cv < 2; ++cv) {
    const float* bias = cv == 0 ? qb : kb;
    u16* OutB = cv == 0 ? QP : KP;
#pragma unroll
    for (int i = 0; i < 4; ++i)
#pragma unroll
      for (int j = 0; j < 2; ++j) {
        int nloc = wn * 32 + j * 16 + lm;
        float bs = bias[nh * 64 + nloc];
#pragma unroll
        for (int rr = 0; rr < 4; ++rr) {
          int m = wm * 64 + i * 16 + lq * 4 + rr;
          T[nloc * 136 + m] = f2bf(acc[cv][i][j][rr] + bs);
        }
      }
    __syncthreads();
#pragma unroll
    for (int it = 0; it < 4; ++it) {
      int item = tid + it * 256;  // 0..1023
      int l = item & 63, cbl = (item >> 6) & 3, ksl = item >> 8;
      int c = cbl * 16 + (l & 15);
      int mloc = ksl * 32 + (l >> 4) * 8;
      int ks = yp * 4 + ksl, cb = nh * 4 + cbl;
      *reinterpret_cast<uint4*>(
          OutB + (size_t)(((b * 128 + ks) * 8 + cb) * 64 + l) * 8) =
          *reinterpret_cast<const uint4*>(T + c * 136 + mloc);
    }
    __syncthreads();
  }

  // ---- V: natural [pos][ch] ----
  u16* Tv = reinterpret_cast<u16*>(Xsb);  // [128][72]
#pragma unroll
  for (int i = 0; i < 4; ++i)
#pragma unroll
    for (int j = 0; j < 2; ++j) {
      int nloc = wn * 32 + j * 16 + lm;
      float bs = vb[nh * 64 + nloc];
#pragma unroll
      for (int rr = 0; rr < 4; ++rr) {
        int m = wm * 64 + i * 16 + lq * 4 + rr;
        Tv[m * 72 + nloc] = f2bf(acc[2][i][j][rr] + bs);
      }
    }
  __syncthreads();
  {
    int rr = tid >> 1, q = tid & 1;
    const uint4* src = reinterpret_cast<const uint4*>(Tv + rr * 72 + q * 32);
    uint4* dst = reinterpret_cast<uint4*>(
        Vout + ((size_t)((b * 32 + yp) * 128 + rr) * 128 + nh * 64 + q * 32));
#pragma unroll
    for (int k = 0; k < 4; ++k) dst[k] = src[k];
  }
}

// ---------------- FFN convs, 3-deep pipeline ----------------
// MODE 1: f1' (per-batch folded weights, gelu -> natural bf16 Hid)
// MODE 3: f2' (f32 NCHW out + inline V@M residual)
template <int MODE>
__global__ __launch_bounds__(256, 2) void conv_gemm(
    const u16* __restrict__ Xin, const u16* __restrict__ Wp,
    const float* __restrict__ bias, u16* __restrict__ OutB,
    float* __restrict__ OutF, const u16* __restrict__ Vin,
    const u16* __restrict__ Mpk) {
  __shared__ alignas(16) char Xsb[4 * 66 * ROWB];  // 71808 B
  const int tid = threadIdx.x;
  const int lane = tid & 63;
  const int wv = tid >> 6;
  const int wm = wv >> 1, wn = wv & 1;
  int mt = blockIdx.x;
  mt = (mt & 7) * 64 + (mt >> 3);
  const int b = mt >> 5;
  const int y0 = (mt & 31) * 2;

  stage_tile(Xin, Xsb, tid, b, y0);
  __syncthreads();

  f32x4 acc[4][4];
#pragma unroll
  for (int i = 0; i < 4; ++i)
#pragma unroll
    for (int j = 0; j < 4; ++j) acc[i][j] = f32x4{0.f, 0.f, 0.f, 0.f};

  const int lm = lane & 15, lq = lane >> 4;
  const int abase = lm * ROWB + lq * 16;
  const u16* wb = Wp + (MODE == 1 ? (size_t)b * 147456 : (size_t)0) +
                  (size_t)((wn * 4 * 64) + lane) * 8;

  auto loada = [&](bf16x8 (&d)[4], int s) {
    int tap = s >> 2, cc = s & 3;
    int dy = (tap * 11) >> 5;
    int dx = tap - dy * 3;
    int roff = ((wm + dy) * 66 + dx) * ROWB + cc * 64 + abase;
#pragma unroll
    for (int i = 0; i < 4; ++i)
      d[i] = *reinterpret_cast<const bf16x8*>(Xsb + roff + i * (16 * ROWB));
  };
  auto loadb = [&](bf16x8 (&d)[4], int s) {
#pragma unroll
    for (int j = 0; j < 4; ++j)
      d[j] = *reinterpret_cast<const bf16x8*>(wb + (size_t)s * 4096 + j * 512);
  };
  auto step = [&](bf16x8 (&a)[4], bf16x8 (&bm)[4]) {
#pragma unroll
    for (int i = 0; i < 4; ++i)
#pragma unroll
      for (int j = 0; j < 4; ++j) acc[i][j] = mfma_bf16(a[i], bm[j], acc[i][j]);
  };

  bf16x8 a0[4], a1[4], a2[4], b0[4], b1[4], b2[4];
  loada(a0, 0); loadb(b0, 0);
  loada(a1, 1); loadb(b1, 1);
  loada(a2, 2); loadb(b2, 2);
#pragma unroll 1
  for (int s = 0; s < 36; s += 3) {
    step(a0, b0);
    if (s + 3 < 36) { loada(a0, s + 3); loadb(b0, s + 3); }
    step(a1, b1);
    if (s + 4 < 36) { loada(a1, s + 4); loadb(b1, s + 4); }
    step(a2, b2);
    if (s + 5 < 36) { loada(a2, s + 5); loadb(b2, s + 5); }
  }

  __syncthreads();

  if (MODE == 1) {
    u16* T = reinterpret_cast<u16*>(Xsb);
#pragma unroll
    for (int i = 0; i < 4; ++i)
#pragma unroll
      for (int j = 0; j < 4; ++j) {
        int n = wn * 64 + j * 16 + lm;
        float bs = bias[n];
#pragma unroll
        for (int r = 0; r < 4; ++r) {
          int m = wm * 64 + i * 16 + lq * 4 + r;
          T[m * 136 + n] = f2bf(gelu_exact(acc[i][j][r] + bs));
        }
      }
    __syncthreads();
    int rr = tid >> 1, hf = tid & 1;
    const uint4* src = reinterpret_cast<const uint4*>(T + rr * 136 + hf * 64);
    uint4* dst = reinterpret_cast<uint4*>(OutB + ((size_t)(mt * 128 + rr) * 128 + hf * 64));
#pragma unroll
    for (int k = 0; k < 8; ++k) dst[k] = src[k];
  } else {
    // inline residual: R = V @ M for this tile (f32, K=128)
    f32x4 accR[4][4];
#pragma unroll
    for (int i = 0; i < 4; ++i)
#pragma unroll
      for (int j = 0; j < 4; ++j) accR[i][j] = f32x4{0.f, 0.f, 0.f, 0.f};
#pragma unroll
    for (int cc = 0; cc < 4; ++cc) {
      int k0 = cc * 32 + lq * 8;
      bf16x8 af[4], bfr[4];
#pragma unroll
      for (int i = 0; i < 4; ++i)
        af[i] = *reinterpret_cast<const bf16x8*>(
            Vin + (size_t)(mt * 128 + wm * 64 + i * 16 + lm) * 128 + k0);
#pragma unroll
      for (int j = 0; j < 4; ++j)
        bfr[j] = *reinterpret_cast<const bf16x8*>(
            Mpk + (size_t)b * 16384 + (size_t)((cc * 8 + wn * 4 + j) * 64 + lane) * 8);
#pragma unroll
      for (int i = 0; i < 4; ++i)
#pragma unroll
        for (int j = 0; j < 4; ++j) accR[i][j] = mfma_bf16(af[i], bfr[j], accR[i][j]);
    }

    float* T = reinterpret_cast<float*>(Xsb);  // [128][132] f32 = 67584 B
#pragma unroll
    for (int i = 0; i < 4; ++i)
#pragma unroll
      for (int j = 0; j < 4; ++j) {
        int n = wn * 64 + j * 16 + lm;
        float bs = bias[n];
#pragma unroll
        for (int r = 0; r < 4; ++r) {
          int m = wm * 64 + i * 16 + lq * 4 + r;
          T[n * 132 + m] = acc[i][j][r] + bs + accR[i][j][r];
        }
      }
    __syncthreads();
    int rr = tid >> 1, hf = tid & 1;
    const uint4* src = reinterpret_cast<const uint4*>(T + rr * 132 + hf * 64);
    uint4* dst = reinterpret_cast<uint4*>(
        OutF + ((size_t)(b * 128 + rr) * 4096 + (mt & 31) * 128 + hf * 64));
#pragma unroll
    for (int k = 0; k < 16; ++k) dst[k] = src[k];
  }
}

// ---------------- S = K^T Q, split-K=8 -> f32 partials ----------------
__global__ __launch_bounds__(256, 2) void attn_s(const u16* __restrict__ QP,
                                                 const u16* __restrict__ KP,
                                                 float* __restrict__ SP) {
  const int tid = threadIdx.x;
  const int lane = tid & 63;
  const int wv = tid >> 6, wm = wv >> 1, wn = wv & 1;
  const int lm = lane & 15, lq = lane >> 4;
  int mt = blockIdx.x;
  mt = (mt & 7) * 16 + (mt >> 3);  // 128 blocks, bijective
  const int b = mt >> 3, sp = mt & 7;

  f32x4 acc[4][4];
#pragma unroll
  for (int i = 0; i < 4; ++i)
#pragma unroll
    for (int j = 0; j < 4; ++j) acc[i][j] = f32x4{0.f, 0.f, 0.f, 0.f};

#pragma unroll
  for (int ksl = 0; ksl < 16; ++ksl) {
    const int ks = sp * 16 + ksl;
    bf16x8 af[4], bfr[4];
#pragma unroll
    for (int i = 0; i < 4; ++i)
      af[i] = *reinterpret_cast<const bf16x8*>(
          KP + (size_t)(((b * 128 + ks) * 8 + wm * 4 + i) * 64 + lane) * 8);
#pragma unroll
    for (int j = 0; j < 4; ++j)
      bfr[j] = *reinterpret_cast<const bf16x8*>(
          QP + (size_t)(((b * 128 + ks) * 8 + wn * 4 + j) * 64 + lane) * 8);
#pragma unroll
    for (int i = 0; i < 4; ++i)
#pragma unroll
      for (int j = 0; j < 4; ++j) acc[i][j] = mfma_bf16(af[i], bfr[j], acc[i][j]);
  }

  float* out = SP + (size_t)(b * 8 + sp) * 16384;
#pragma unroll
  for (int i = 0; i < 4; ++i)
#pragma unroll
    for (int j = 0; j < 4; ++j)
#pragma unroll
      for (int r = 0; r < 4; ++r)
        out[(wm * 64 + i * 16 + lq * 4 + r) * 128 + wn * 64 + j * 16 + lm] =
            acc[i][j][r];
}

// ---- fused: reduce partials + softmax + M=Pspe@A + pack M both ways -------
__global__ __launch_bounds__(256, 1) void attn_rm(const float* __restrict__ SP,
                                                  const float* __restrict__ Pspe,
                                                  u16* __restrict__ Mpack,
                                                  u16* __restrict__ Mpack2) {
  __shared__ float Sf[128 * 129];  // 66048 B
  __shared__ u16 AT[128 * 136];    // 34816 B
  const int b = blockIdx.x;
  const int tid = threadIdx.x;
  const int lane = tid & 63;
  const int wv = tid >> 6, wm = wv >> 1, wn = wv & 1;
  const int lm = lane & 15, lq = lane >> 4;

#pragma unroll
  for (int it = 0; it < 64; ++it) {
    int id = it * 256 + tid;
    int rl = id >> 7, d = id & 127;
    const float* p = SP + (size_t)b * 8 * 16384 + (size_t)rl * 128 + d;
    float s = 0.f;
#pragma unroll
    for (int sp = 0; sp < 8; ++sp) s += p[(size_t)sp * 16384];
    Sf[rl * 129 + d] = s * 0.015625f;  // /sqrt(4096)
  }
  __syncthreads();

  {
    int c = tid >> 1, hf = tid & 1;
    float* row = Sf + c * 129 + hf * 64;
    float mx = -3.4e38f;
#pragma unroll
    for (int k = 0; k < 64; ++k) mx = fmaxf(mx, row[k]);
    mx = fmaxf(mx, __shfl_xor(mx, 1));
    float s = 0.f;
#pragma unroll
    for (int k = 0; k < 64; ++k) {
      float e = __expf(row[k] - mx);
      row[k] = e;
      s += e;
    }
    s += __shfl_xor(s, 1);
    float inv = 1.0f / s;
#pragma unroll
    for (int k = 0; k < 64; ++k) AT[(hf * 64 + k) * 136 + c] = f2bf(row[k] * inv);
  }
  __syncthreads();

  // M = Pspe @ A
  f32x4 acc2[4][4];
#pragma unroll
  for (int i = 0; i < 4; ++i)
#pragma unroll
    for (int j = 0; j < 4; ++j) acc2[i][j] = f32x4{0.f, 0.f, 0.f, 0.f};
  const float* P = Pspe + (size_t)b * 128 * 128;
#pragma unroll
  for (int cc = 0; cc < 4; ++cc) {
    int e0 = cc * 32 + lq * 8;
    bf16x8 af[4], bfr[4];
#pragma unroll
    for (int i = 0; i < 4; ++i) {
      const float* p = P + (size_t)(wm * 64 + i * 16 + lm) * 128 + e0;
      union { u16 u[8]; bf16x8 v; } cvt;
#pragma unroll
      for (int e = 0; e < 8; ++e) cvt.u[e] = f2bf(p[e]);
      af[i] = cvt.v;
    }
#pragma unroll
    for (int j = 0; j < 4; ++j)
      bfr[j] = *reinterpret_cast<const bf16x8*>(AT + (wn * 64 + j * 16 + lm) * 136 + e0);
#pragma unroll
    for (int i = 0; i < 4; ++i)
#pragma unroll
      for (int j = 0; j < 4; ++j) acc2[i][j] = mfma_bf16(af[i], bfr[j], acc2[i][j]);
  }

  // M^T [d][c] into Ml (aliases Sf)
  u16* Ml = reinterpret_cast<u16*>(Sf);  // [128][136]
#pragma unroll
  for (int i = 0; i < 4; ++i)
#pragma unroll
    for (int j = 0; j < 4; ++j)
#pragma unroll
      for (int r = 0; r < 4; ++r)
        Ml[(wn * 64 + j * 16 + lm) * 136 + (wm * 64 + i * 16 + lq * 4 + r)] =
            f2bf(acc2[i][j][r]);
  __syncthreads();

  // Mpack: fragments with (frag-row = d, k = c)  [for f2' V@M residual]
#pragma unroll
  for (int it = 0; it < 8; ++it) {
    int item = tid + it * 256;
    int l2 = item & 63, nb = (item >> 6) & 7, cc2 = item >> 9;
    int d = nb * 16 + (l2 & 15), c0 = cc2 * 32 + (l2 >> 4) * 8;
    *reinterpret_cast<uint4*>(Mpack + (size_t)b * 16384 + (size_t)item * 8) =
        *reinterpret_cast<const uint4*>(Ml + d * 136 + c0);
  }
  // Mpack2: fragments with (frag-row = c, k = d)  [for wfold1]
#pragma unroll
  for (int it = 0; it < 8; ++it) {
    int item = tid + it * 256;
    int l2 = item & 63, nb = (item >> 6) & 7, cc2 = item >> 9;
    int c = nb * 16 + (l2 & 15), d0 = cc2 * 32 + (l2 >> 4) * 8;
    u16 tmp[8];
#pragma unroll
    for (int e = 0; e < 8; ++e) tmp[e] = Ml[(d0 + e) * 136 + c];
    *reinterpret_cast<uint4*>(Mpack2 + (size_t)b * 16384 + (size_t)item * 8) =
        *reinterpret_cast<const uint4*>(tmp);
  }
}

// ---- wfold1: W1'[co][c,tap] = sum_d W1[co][d,tap] * M[c][d] ---------------
__global__ __launch_bounds__(256, 2) void wfold1(const u16* __restrict__ W1pk,
                                                 const u16* __restrict__ Mpk2,
                                                 u16* __restrict__ Wf1) {
  __shared__ u16 T[128 * 136];
  const int tid = threadIdx.x;
  const int lane = tid & 63, wv = tid >> 6;
  const int wm = wv >> 1, wn = wv & 1;
  const int lm = lane & 15, lq = lane >> 4;
  const int b = blockIdx.x / 9, tap = blockIdx.x % 9;

  f32x4 acc[4][4];
#pragma unroll
  for (int i = 0; i < 4; ++i)
#pragma unroll
    for (int j = 0; j < 4; ++j) acc[i][j] = f32x4{0.f, 0.f, 0.f, 0.f};

#pragma unroll
  for (int cc = 0; cc < 4; ++cc) {
    bf16x8 af[4], bfr[4];
#pragma unroll
    for (int i = 0; i < 4; ++i)
      af[i] = *reinterpret_cast<const bf16x8*>(
          W1pk + (size_t)(((tap * 4 + cc) * 8 + wm * 4 + i) * 64 + lane) * 8);
#pragma unroll
    for (int j = 0; j < 4; ++j)
      bfr[j] = *reinterpret_cast<const bf16x8*>(
          Mpk2 + (size_t)b * 16384 + (size_t)((cc * 8 + wn * 4 + j) * 64 + lane) * 8);
#pragma unroll
    for (int i = 0; i < 4; ++i)
#pragma unroll
      for (int j = 0; j < 4; ++j) acc[i][j] = mfma_bf16(af[i], bfr[j], acc[i][j]);
  }

#pragma unroll
  for (int i = 0; i < 4; ++i)
#pragma unroll
    for (int j = 0; j < 4; ++j)
#pragma unroll
      for (int r = 0; r < 4; ++r)
        T[(wm * 64 + i * 16 + lq * 4 + r) * 136 + wn * 64 + j * 16 + lm] =
            f2bf(acc[i][j][r]);
  __syncthreads();

#pragma unroll
  for (int it = 0; it < 8; ++it) {
    int item = tid + it * 256;  // 0..2047
    int L = item & 63, nb = (item >> 6) & 7, cc2 = item >> 9;
    int co = nb * 16 + (L & 15);
    int c0 = cc2 * 32 + (L >> 4) * 8;
    *reinterpret_cast<uint4*>(
        Wf1 + (size_t)b * 147456 +
        ((size_t)(((tap * 4 + cc2) * 8 + nb) * 64 + L)) * 8) =
        *reinterpret_cast<const uint4*>(T + co * 136 + c0);
  }
}

extern "C" void kernel_launch(void* const* d_in, const int* in_sizes, int n_in,
                              void* d_out, int out_size, void* d_ws, size_t ws_size,
                              hipStream_t stream) {
  const float* F_in = (const float*)d_in[0];
  const float* Pspe = (const float*)d_in[1];
  const float* q_w = (const float*)d_in[2];
  const float* q_b = (const float*)d_in[3];
  const float* k_w = (const float*)d_in[4];
  const float* k_b = (const float*)d_in[5];
  const float* v_w = (const float*)d_in[6];
  const float* v_b = (const float*)d_in[7];
  const float* f1_w = (const float*)d_in[8];
  const float* f1_b = (const float*)d_in[9];
  const float* f2_w = (const float*)d_in[10];
  const float* f2_b = (const float*)d_in[11];
  float* out = (float*)d_out;

  char* ws = (char*)d_ws;
  const size_t SZ = 16777216;  // 65536*128*2 bytes
  u16* X = (u16*)(ws);                   // NHWC bf16 input; SP aliases later
  u16* QP = (u16*)(ws + SZ);             // packed Q; later Hid
  u16* KP = (u16*)(ws + 2 * SZ);         // packed K
  u16* V = (u16*)(ws + 3 * SZ);          // natural V (alive until f2')
  u16* Wpk = (u16*)(ws + 4 * SZ);                    // 1,474,560 B
  u16* Mpk = (u16*)(ws + 4 * SZ + 1474560);          // 524,288 B
  u16* Mpk2 = (u16*)(ws + 4 * SZ + 1998848);         // 524,288 B
  u16* Wf1 = (u16*)(ws + 4 * SZ + 2523136);          // 4,718,592 B -> ~74.4 MB
  float* SP = (float*)ws;                // 8.39 MB partials — aliases X (dead)
  u16* Hid = QP;                         // f1' output — aliases QP (dead)

  pack_xw<<<1384, 256, 0, stream>>>(F_in, X, q_w, k_w, v_w, f1_w, f2_w, Wpk);
  conv_qkv<<<1024, 256, 0, stream>>>(X, Wpk, q_b, k_b, v_b, QP, KP, V);
  attn_s<<<128, 256, 0, stream>>>(QP, KP, SP);
  attn_rm<<<16, 256, 0, stream>>>(SP, Pspe, Mpk, Mpk2);
  wfold1<<<144, 256, 0, stream>>>(Wpk + 3 * 147456, Mpk2, Wf1);
  conv_gemm<1><<<512, 256, 0, stream>>>(V, Wf1, f1_b, Hid, nullptr, nullptr,
                                        nullptr);
  conv_gemm<3><<<512, 256, 0, stream>>>(Hid, Wpk + 4 * 147456, f2_b, nullptr,
                                        out, V, Mpk);
}

// Round 15
// 168.975 us; speedup vs baseline: 1.0619x; 1.0093x over previous
//
#include <hip/hip_runtime.h>
#include <cmath>

typedef unsigned short u16;
typedef __bf16 bf16x8 __attribute__((ext_vector_type(8)));
typedef float f32x4 __attribute__((ext_vector_type(4)));

__device__ __forceinline__ u16 f2bf(float f) {
  unsigned u = __float_as_uint(f);
  u += 0x7fffu + ((u >> 16) & 1u);
  return (u16)(u >> 16);
}
__device__ __forceinline__ float bf2f(u16 h) {
  return __uint_as_float(((unsigned)h) << 16);
}
__device__ __forceinline__ f32x4 mfma_bf16(bf16x8 a, bf16x8 b, f32x4 c) {
  return __builtin_amdgcn_mfma_f32_16x16x32_bf16(a, b, c, 0, 0, 0);
}
__device__ __forceinline__ float gelu_exact(float x) {
  return 0.5f * x * (1.0f + erff(x * 0.70710678118654752440f));
}

// B=16, C=128, H=64, W=64, HW=4096, NPOS=65536
// LDS A-tile: [4*66 rows][136 u16] — 272B row stride (128ch + 8 pad).
#define ROWB 272

// ---------------- merged pack: X (NCHW f32 -> NHWC bf16) + weights ----------
__global__ __launch_bounds__(256) void pack_xw(
    const float* __restrict__ Fin, u16* __restrict__ X,
    const float* __restrict__ w0, const float* __restrict__ w1,
    const float* __restrict__ w2, const float* __restrict__ w3,
    const float* __restrict__ w4, u16* __restrict__ Wpk) {
  __shared__ float T[64 * 129];
  const int tid = threadIdx.x;
  if (blockIdx.x < 1024) {
    const int b = blockIdx.x >> 6, y = blockIdx.x & 63;
#pragma unroll
    for (int i = 0; i < 32; ++i) {
      int idx = tid + i * 256;
      int c = idx >> 6, x = idx & 63;
      T[x * 129 + c] = Fin[(size_t)(b * 128 + c) * 4096 + y * 64 + x];
    }
    __syncthreads();
#pragma unroll
    for (int i = 0; i < 4; ++i) {
      int chunk = tid + i * 256;
      int x = chunk >> 4;
      int c0 = (chunk & 15) * 8;
      u16 tmp[8];
#pragma unroll
      for (int e = 0; e < 8; ++e) tmp[e] = f2bf(T[x * 129 + c0 + e]);
      *reinterpret_cast<uint4*>(X + ((size_t)((b * 64 + y) * 64 + x) * 128 + c0)) =
          *reinterpret_cast<const uint4*>(tmp);
    }
  } else {
    int gid = (blockIdx.x - 1024) * 256 + tid;  // 92160 total
    int lane = gid & 63;
    int nblk = (gid >> 6) & 7;
    int step = (gid >> 9) % 36;
    int conv = gid / (512 * 36);
    if (conv >= 5) return;
    const float* w = conv == 0 ? w0 : conv == 1 ? w1 : conv == 2 ? w2 : conv == 3 ? w3 : w4;
    int tap = step >> 2, cc = step & 3;
    int dy = tap / 3, dx = tap % 3;
    int co = nblk * 16 + (lane & 15);
    int ci0 = cc * 32 + (lane >> 4) * 8;
    u16 tmp[8];
#pragma unroll
    for (int e = 0; e < 8; ++e)
      tmp[e] = f2bf(w[((size_t)(co * 128 + ci0 + e) * 3 + dy) * 3 + dx]);
    size_t off = ((size_t)conv * 36 * 8 * 64 + (size_t)((step * 8 + nblk) * 64 + lane)) * 8;
    *reinterpret_cast<uint4*>(Wpk + off) = *reinterpret_cast<const uint4*>(tmp);
  }
}

// ======== staging: rows y0-1..y0+2, x-halo, linear 272B-stride layout ======
__device__ __forceinline__ void stage_tile(const u16* __restrict__ Xin, char* Xsb,
                                           int tid, int b, int y0) {
#pragma unroll
  for (int i = 0; i < 16; ++i) {
    int j = tid + i * 256;
    int row = j >> 4;
    int c16 = j & 15;
    int ys = row >> 6, x = row & 63;
    int ysrc = y0 - 1 + ys;
    uint4 val = make_uint4(0u, 0u, 0u, 0u);
    if ((unsigned)ysrc < 64u)
      val = *reinterpret_cast<const uint4*>(
          Xin + ((size_t)((b * 64 + ysrc) * 64 + x) * 128 + c16 * 8));
    *reinterpret_cast<uint4*>(Xsb + (ys * 66 + x + 1) * ROWB + c16 * 16) = val;
  }
  if (tid < 128) {
    int ys = tid >> 5, side = (tid >> 4) & 1, c16 = tid & 15;
    int xs = side ? 65 : 0;
    *reinterpret_cast<uint4*>(Xsb + (ys * 66 + xs) * ROWB + c16 * 16) =
        make_uint4(0u, 0u, 0u, 0u);
  }
}

// ---------------- fused QKV conv3x3, M128xN64, pinned 3-deep pipeline -------
__global__ __launch_bounds__(256, 2) void conv_qkv(
    const u16* __restrict__ Xin, const u16* __restrict__ Wp,
    const float* __restrict__ qb, const float* __restrict__ kb,
    const float* __restrict__ vb, u16* __restrict__ QP,
    u16* __restrict__ KP, u16* __restrict__ Vout) {
  __shared__ alignas(16) char Xsb[4 * 66 * ROWB];  // 71808 B
  const int tid = threadIdx.x;
  const int lane = tid & 63;
  const int wv = tid >> 6;
  const int wm = wv >> 1, wn = wv & 1;
  int mt = blockIdx.x;
  mt = (mt & 7) * 128 + (mt >> 3);  // 1024 blocks, bijective XCD swizzle
  const int b = mt >> 6;
  const int r = mt & 63;
  const int yp = r >> 1;      // y-pair 0..31
  const int nh = r & 1;       // N half
  const int y0 = yp * 2;

  stage_tile(Xin, Xsb, tid, b, y0);
  __syncthreads();

  f32x4 acc[3][4][2];
#pragma unroll
  for (int c = 0; c < 3; ++c)
#pragma unroll
    for (int i = 0; i < 4; ++i)
#pragma unroll
      for (int j = 0; j < 2; ++j) acc[c][i][j] = f32x4{0.f, 0.f, 0.f, 0.f};

  const int lm = lane & 15, lq = lane >> 4;
  const int abase = lm * ROWB + lq * 16;
  const u16* wb = Wp + (size_t)(((nh * 4 + wn * 2) * 64) + lane) * 8;

  auto loada = [&](bf16x8 (&d)[4], int s) {
    int tap = s >> 2, cc = s & 3;
    int dy = (tap * 11) >> 5;
    int dx = tap - dy * 3;
    int roff = ((wm + dy) * 66 + dx) * ROWB + cc * 64 + abase;
#pragma unroll
    for (int i = 0; i < 4; ++i)
      d[i] = *reinterpret_cast<const bf16x8*>(Xsb + roff + i * (16 * ROWB));
  };
  auto loadb = [&](bf16x8 (&d)[6], int s) {
#pragma unroll
    for (int cv = 0; cv < 3; ++cv)
#pragma unroll
      for (int j = 0; j < 2; ++j)
        d[cv * 2 + j] = *reinterpret_cast<const bf16x8*>(
            wb + (size_t)cv * 147456 + (size_t)s * 4096 + j * 512);
  };
  auto step = [&](bf16x8 (&a)[4], bf16x8 (&bm)[6]) {
#pragma unroll
    for (int cv = 0; cv < 3; ++cv)
#pragma unroll
      for (int i = 0; i < 4; ++i)
#pragma unroll
        for (int j = 0; j < 2; ++j)
          acc[cv][i][j] = mfma_bf16(a[i], bm[cv * 2 + j], acc[cv][i][j]);
  };

  bf16x8 a0[4], a1[4], a2[4], b0[6], b1[6], b2[6];
  loada(a0, 0); loadb(b0, 0);
  loada(a1, 1); loadb(b1, 1);
  loada(a2, 2); loadb(b2, 2);
#pragma unroll 1
  for (int s = 0; s < 36; s += 3) {
    step(a0, b0);
    {
      int t = s + 3 < 36 ? s + 3 : 33;
      loada(a0, t); loadb(b0, t);
    }
    __builtin_amdgcn_sched_barrier(0);
    step(a1, b1);
    {
      int t = s + 4 < 36 ? s + 4 : 34;
      loada(a1, t); loadb(b1, t);
    }
    __builtin_amdgcn_sched_barrier(0);
    step(a2, b2);
    {
      int t = s + 5 < 36 ? s + 5 : 35;
      loada(a2, t); loadb(b2, t);
    }
    __builtin_amdgcn_sched_barrier(0);
  }

  __syncthreads();  // Xs dead; reuse for epilogues

  // ---- Q, K: fragment-packed epilogue ----
  u16* T = reinterpret_cast<u16*>(Xsb);  // [64][136]
#pragma unroll
  for (int cv = 0; cv < 2; ++cv) {
    const float* bias = cv == 0 ? qb : kb;
    u16* OutB = cv == 0 ? QP : KP;
#pragma unroll
    for (int i = 0; i < 4; ++i)
#pragma unroll
      for (int j = 0; j < 2; ++j) {
        int nloc = wn * 32 + j * 16 + lm;
        float bs = bias[nh * 64 + nloc];
#pragma unroll
        for (int rr = 0; rr < 4; ++rr) {
          int m = wm * 64 + i * 16 + lq * 4 + rr;
          T[nloc * 136 + m] = f2bf(acc[cv][i][j][rr] + bs);
        }
      }
    __syncthreads();
#pragma unroll
    for (int it = 0; it < 4; ++it) {
      int item = tid + it * 256;  // 0..1023
      int l = item & 63, cbl = (item >> 6) & 3, ksl = item >> 8;
      int c = cbl * 16 + (l & 15);
      int mloc = ksl * 32 + (l >> 4) * 8;
      int ks = yp * 4 + ksl, cb = nh * 4 + cbl;
      *reinterpret_cast<uint4*>(
          OutB + (size_t)(((b * 128 + ks) * 8 + cb) * 64 + l) * 8) =
          *reinterpret_cast<const uint4*>(T + c * 136 + mloc);
    }
    __syncthreads();
  }

  // ---- V: natural [pos][ch] ----
  u16* Tv = reinterpret_cast<u16*>(Xsb);  // [128][72]
#pragma unroll
  for (int i = 0; i < 4; ++i)
#pragma unroll
    for (int j = 0; j < 2; ++j) {
      int nloc = wn * 32 + j * 16 + lm;
      float bs = vb[nh * 64 + nloc];
#pragma unroll
      for (int rr = 0; rr < 4; ++rr) {
        int m = wm * 64 + i * 16 + lq * 4 + rr;
        Tv[m * 72 + nloc] = f2bf(acc[2][i][j][rr] + bs);
      }
    }
  __syncthreads();
  {
    int rr = tid >> 1, q = tid & 1;
    const uint4* src = reinterpret_cast<const uint4*>(Tv + rr * 72 + q * 32);
    uint4* dst = reinterpret_cast<uint4*>(
        Vout + ((size_t)((b * 32 + yp) * 128 + rr) * 128 + nh * 64 + q * 32));
#pragma unroll
    for (int k = 0; k < 4; ++k) dst[k] = src[k];
  }
}

// ---------------- FFN convs, pinned 3-deep pipeline ----------------
// MODE 1: f1' (per-batch folded weights, gelu -> natural bf16 Hid)
// MODE 3: f2' (f32 NCHW out + inline V@M residual)
template <int MODE>
__global__ __launch_bounds__(256, 2) void conv_gemm(
    const u16* __restrict__ Xin, const u16* __restrict__ Wp,
    const float* __restrict__ bias, u16* __restrict__ OutB,
    float* __restrict__ OutF, const u16* __restrict__ Vin,
    const u16* __restrict__ Mpk) {
  __shared__ alignas(16) char Xsb[4 * 66 * ROWB];  // 71808 B
  const int tid = threadIdx.x;
  const int lane = tid & 63;
  const int wv = tid >> 6;
  const int wm = wv >> 1, wn = wv & 1;
  int mt = blockIdx.x;
  mt = (mt & 7) * 64 + (mt >> 3);
  const int b = mt >> 5;
  const int y0 = (mt & 31) * 2;

  stage_tile(Xin, Xsb, tid, b, y0);
  __syncthreads();

  f32x4 acc[4][4];
#pragma unroll
  for (int i = 0; i < 4; ++i)
#pragma unroll
    for (int j = 0; j < 4; ++j) acc[i][j] = f32x4{0.f, 0.f, 0.f, 0.f};

  const int lm = lane & 15, lq = lane >> 4;
  const int abase = lm * ROWB + lq * 16;
  const u16* wb = Wp + (MODE == 1 ? (size_t)b * 147456 : (size_t)0) +
                  (size_t)((wn * 4 * 64) + lane) * 8;

  auto loada = [&](bf16x8 (&d)[4], int s) {
    int tap = s >> 2, cc = s & 3;
    int dy = (tap * 11) >> 5;
    int dx = tap - dy * 3;
    int roff = ((wm + dy) * 66 + dx) * ROWB + cc * 64 + abase;
#pragma unroll
    for (int i = 0; i < 4; ++i)
      d[i] = *reinterpret_cast<const bf16x8*>(Xsb + roff + i * (16 * ROWB));
  };
  auto loadb = [&](bf16x8 (&d)[4], int s) {
#pragma unroll
    for (int j = 0; j < 4; ++j)
      d[j] = *reinterpret_cast<const bf16x8*>(wb + (size_t)s * 4096 + j * 512);
  };
  auto step = [&](bf16x8 (&a)[4], bf16x8 (&bm)[4]) {
#pragma unroll
    for (int i = 0; i < 4; ++i)
#pragma unroll
      for (int j = 0; j < 4; ++j) acc[i][j] = mfma_bf16(a[i], bm[j], acc[i][j]);
  };

  bf16x8 a0[4], a1[4], a2[4], b0[4], b1[4], b2[4];
  loada(a0, 0); loadb(b0, 0);
  loada(a1, 1); loadb(b1, 1);
  loada(a2, 2); loadb(b2, 2);
#pragma unroll 1
  for (int s = 0; s < 36; s += 3) {
    step(a0, b0);
    {
      int t = s + 3 < 36 ? s + 3 : 33;
      loada(a0, t); loadb(b0, t);
    }
    __builtin_amdgcn_sched_barrier(0);
    step(a1, b1);
    {
      int t = s + 4 < 36 ? s + 4 : 34;
      loada(a1, t); loadb(b1, t);
    }
    __builtin_amdgcn_sched_barrier(0);
    step(a2, b2);
    {
      int t = s + 5 < 36 ? s + 5 : 35;
      loada(a2, t); loadb(b2, t);
    }
    __builtin_amdgcn_sched_barrier(0);
  }

  __syncthreads();

  if (MODE == 1) {
    u16* T = reinterpret_cast<u16*>(Xsb);
#pragma unroll
    for (int i = 0; i < 4; ++i)
#pragma unroll
      for (int j = 0; j < 4; ++j) {
        int n = wn * 64 + j * 16 + lm;
        float bs = bias[n];
#pragma unroll
        for (int r = 0; r < 4; ++r) {
          int m = wm * 64 + i * 16 + lq * 4 + r;
          T[m * 136 + n] = f2bf(gelu_exact(acc[i][j][r] + bs));
        }
      }
    __syncthreads();
    int rr = tid >> 1, hf = tid & 1;
    const uint4* src = reinterpret_cast<const uint4*>(T + rr * 136 + hf * 64);
    uint4* dst = reinterpret_cast<uint4*>(OutB + ((size_t)(mt * 128 + rr) * 128 + hf * 64));
#pragma unroll
    for (int k = 0; k < 8; ++k) dst[k] = src[k];
  } else {
    // inline residual: R = V @ M for this tile (f32, K=128)
    f32x4 accR[4][4];
#pragma unroll
    for (int i = 0; i < 4; ++i)
#pragma unroll
      for (int j = 0; j < 4; ++j) accR[i][j] = f32x4{0.f, 0.f, 0.f, 0.f};
#pragma unroll
    for (int cc = 0; cc < 4; ++cc) {
      int k0 = cc * 32 + lq * 8;
      bf16x8 af[4], bfr[4];
#pragma unroll
      for (int i = 0; i < 4; ++i)
        af[i] = *reinterpret_cast<const bf16x8*>(
            Vin + (size_t)(mt * 128 + wm * 64 + i * 16 + lm) * 128 + k0);
#pragma unroll
      for (int j = 0; j < 4; ++j)
        bfr[j] = *reinterpret_cast<const bf16x8*>(
            Mpk + (size_t)b * 16384 + (size_t)((cc * 8 + wn * 4 + j) * 64 + lane) * 8);
#pragma unroll
      for (int i = 0; i < 4; ++i)
#pragma unroll
        for (int j = 0; j < 4; ++j) accR[i][j] = mfma_bf16(af[i], bfr[j], accR[i][j]);
    }

    float* T = reinterpret_cast<float*>(Xsb);  // [128][132] f32 = 67584 B
#pragma unroll
    for (int i = 0; i < 4; ++i)
#pragma unroll
      for (int j = 0; j < 4; ++j) {
        int n = wn * 64 + j * 16 + lm;
        float bs = bias[n];
#pragma unroll
        for (int r = 0; r < 4; ++r) {
          int m = wm * 64 + i * 16 + lq * 4 + r;
          T[n * 132 + m] = acc[i][j][r] + bs + accR[i][j][r];
        }
      }
    __syncthreads();
    int rr = tid >> 1, hf = tid & 1;
    const uint4* src = reinterpret_cast<const uint4*>(T + rr * 132 + hf * 64);
    uint4* dst = reinterpret_cast<uint4*>(
        OutF + ((size_t)(b * 128 + rr) * 4096 + (mt & 31) * 128 + hf * 64));
#pragma unroll
    for (int k = 0; k < 16; ++k) dst[k] = src[k];
  }
}

// ---------------- S = K^T Q, split-K=8 -> f32 partials ----------------
__global__ __launch_bounds__(256, 2) void attn_s(const u16* __restrict__ QP,
                                                 const u16* __restrict__ KP,
                                                 float* __restrict__ SP) {
  const int tid = threadIdx.x;
  const int lane = tid & 63;
  const int wv = tid >> 6, wm = wv >> 1, wn = wv & 1;
  const int lm = lane & 15, lq = lane >> 4;
  int mt = blockIdx.x;
  mt = (mt & 7) * 16 + (mt >> 3);  // 128 blocks, bijective
  const int b = mt >> 3, sp = mt & 7;

  f32x4 acc[4][4];
#pragma unroll
  for (int i = 0; i < 4; ++i)
#pragma unroll
    for (int j = 0; j < 4; ++j) acc[i][j] = f32x4{0.f, 0.f, 0.f, 0.f};

#pragma unroll
  for (int ksl = 0; ksl < 16; ++ksl) {
    const int ks = sp * 16 + ksl;
    bf16x8 af[4], bfr[4];
#pragma unroll
    for (int i = 0; i < 4; ++i)
      af[i] = *reinterpret_cast<const bf16x8*>(
          KP + (size_t)(((b * 128 + ks) * 8 + wm * 4 + i) * 64 + lane) * 8);
#pragma unroll
    for (int j = 0; j < 4; ++j)
      bfr[j] = *reinterpret_cast<const bf16x8*>(
          QP + (size_t)(((b * 128 + ks) * 8 + wn * 4 + j) * 64 + lane) * 8);
#pragma unroll
    for (int i = 0; i < 4; ++i)
#pragma unroll
      for (int j = 0; j < 4; ++j) acc[i][j] = mfma_bf16(af[i], bfr[j], acc[i][j]);
  }

  float* out = SP + (size_t)(b * 8 + sp) * 16384;
#pragma unroll
  for (int i = 0; i < 4; ++i)
#pragma unroll
    for (int j = 0; j < 4; ++j)
#pragma unroll
      for (int r = 0; r < 4; ++r)
        out[(wm * 64 + i * 16 + lq * 4 + r) * 128 + wn * 64 + j * 16 + lm] =
            acc[i][j][r];
}

// ---- fused: reduce partials + softmax + M=Pspe@A + pack M both ways -------
__global__ __launch_bounds__(256, 1) void attn_rm(const float* __restrict__ SP,
                                                  const float* __restrict__ Pspe,
                                                  u16* __restrict__ Mpack,
                                                  u16* __restrict__ Mpack2) {
  __shared__ float Sf[128 * 129];  // 66048 B
  __shared__ u16 AT[128 * 136];    // 34816 B
  const int b = blockIdx.x;
  const int tid = threadIdx.x;
  const int lane = tid & 63;
  const int wv = tid >> 6, wm = wv >> 1, wn = wv & 1;
  const int lm = lane & 15, lq = lane >> 4;

#pragma unroll
  for (int it = 0; it < 64; ++it) {
    int id = it * 256 + tid;
    int rl = id >> 7, d = id & 127;
    const float* p = SP + (size_t)b * 8 * 16384 + (size_t)rl * 128 + d;
    float s = 0.f;
#pragma unroll
    for (int sp = 0; sp < 8; ++sp) s += p[(size_t)sp * 16384];
    Sf[rl * 129 + d] = s * 0.015625f;  // /sqrt(4096)
  }
  __syncthreads();

  {
    int c = tid >> 1, hf = tid & 1;
    float* row = Sf + c * 129 + hf * 64;
    float mx = -3.4e38f;
#pragma unroll
    for (int k = 0; k < 64; ++k) mx = fmaxf(mx, row[k]);
    mx = fmaxf(mx, __shfl_xor(mx, 1));
    float s = 0.f;
#pragma unroll
    for (int k = 0; k < 64; ++k) {
      float e = __expf(row[k] - mx);
      row[k] = e;
      s += e;
    }
    s += __shfl_xor(s, 1);
    float inv = 1.0f / s;
#pragma unroll
    for (int k = 0; k < 64; ++k) AT[(hf * 64 + k) * 136 + c] = f2bf(row[k] * inv);
  }
  __syncthreads();

  // M = Pspe @ A
  f32x4 acc2[4][4];
#pragma unroll
  for (int i = 0; i < 4; ++i)
#pragma unroll
    for (int j = 0; j < 4; ++j) acc2[i][j] = f32x4{0.f, 0.f, 0.f, 0.f};
  const float* P = Pspe + (size_t)b * 128 * 128;
#pragma unroll
  for (int cc = 0; cc < 4; ++cc) {
    int e0 = cc * 32 + lq * 8;
    bf16x8 af[4], bfr[4];
#pragma unroll
    for (int i = 0; i < 4; ++i) {
      const float* p = P + (size_t)(wm * 64 + i * 16 + lm) * 128 + e0;
      union { u16 u[8]; bf16x8 v; } cvt;
#pragma unroll
      for (int e = 0; e < 8; ++e) cvt.u[e] = f2bf(p[e]);
      af[i] = cvt.v;
    }
#pragma unroll
    for (int j = 0; j < 4; ++j)
      bfr[j] = *reinterpret_cast<const bf16x8*>(AT + (wn * 64 + j * 16 + lm) * 136 + e0);
#pragma unroll
    for (int i = 0; i < 4; ++i)
#pragma unroll
      for (int j = 0; j < 4; ++j) acc2[i][j] = mfma_bf16(af[i], bfr[j], acc2[i][j]);
  }

  // M^T [d][c] into Ml (aliases Sf)
  u16* Ml = reinterpret_cast<u16*>(Sf);  // [128][136]
#pragma unroll
  for (int i = 0; i < 4; ++i)
#pragma unroll
    for (int j = 0; j < 4; ++j)
#pragma unroll
      for (int r = 0; r < 4; ++r)
        Ml[(wn * 64 + j * 16 + lm) * 136 + (wm * 64 + i * 16 + lq * 4 + r)] =
            f2bf(acc2[i][j][r]);
  __syncthreads();

  // Mpack: fragments with (frag-row = d, k = c)  [for f2' V@M residual]
#pragma unroll
  for (int it = 0; it < 8; ++it) {
    int item = tid + it * 256;
    int l2 = item & 63, nb = (item >> 6) & 7, cc2 = item >> 9;
    int d = nb * 16 + (l2 & 15), c0 = cc2 * 32 + (l2 >> 4) * 8;
    *reinterpret_cast<uint4*>(Mpack + (size_t)b * 16384 + (size_t)item * 8) =
        *reinterpret_cast<const uint4*>(Ml + d * 136 + c0);
  }
  // Mpack2: fragments with (frag-row = c, k = d)  [for wfold1]
#pragma unroll
  for (int it = 0; it < 8; ++it) {
    int item = tid + it * 256;
    int l2 = item & 63, nb = (item >> 6) & 7, cc2 = item >> 9;
    int c = nb * 16 + (l2 & 15), d0 = cc2 * 32 + (l2 >> 4) * 8;
    u16 tmp[8];
#pragma unroll
    for (int e = 0; e < 8; ++e) tmp[e] = Ml[(d0 + e) * 136 + c];
    *reinterpret_cast<uint4*>(Mpack2 + (size_t)b * 16384 + (size_t)item * 8) =
        *reinterpret_cast<const uint4*>(tmp);
  }
}

// ---- wfold1: W1'[co][c,tap] = sum_d W1[co][d,tap] * M[c][d] ---------------
__global__ __launch_bounds__(256, 2) void wfold1(const u16* __restrict__ W1pk,
                                                 const u16* __restrict__ Mpk2,
                                                 u16* __restrict__ Wf1) {
  __shared__ u16 T[128 * 136];
  const int tid = threadIdx.x;
  const int lane = tid & 63, wv = tid >> 6;
  const int wm = wv >> 1, wn = wv & 1;
  const int lm = lane & 15, lq = lane >> 4;
  const int b = blockIdx.x / 9, tap = blockIdx.x % 9;

  f32x4 acc[4][4];
#pragma unroll
  for (int i = 0; i < 4; ++i)
#pragma unroll
    for (int j = 0; j < 4; ++j) acc[i][j] = f32x4{0.f, 0.f, 0.f, 0.f};

#pragma unroll
  for (int cc = 0; cc < 4; ++cc) {
    bf16x8 af[4], bfr[4];
#pragma unroll
    for (int i = 0; i < 4; ++i)
      af[i] = *reinterpret_cast<const bf16x8*>(
          W1pk + (size_t)(((tap * 4 + cc) * 8 + wm * 4 + i) * 64 + lane) * 8);
#pragma unroll
    for (int j = 0; j < 4; ++j)
      bfr[j] = *reinterpret_cast<const bf16x8*>(
          Mpk2 + (size_t)b * 16384 + (size_t)((cc * 8 + wn * 4 + j) * 64 + lane) * 8);
#pragma unroll
    for (int i = 0; i < 4; ++i)
#pragma unroll
      for (int j = 0; j < 4; ++j) acc[i][j] = mfma_bf16(af[i], bfr[j], acc[i][j]);
  }

#pragma unroll
  for (int i = 0; i < 4; ++i)
#pragma unroll
    for (int j = 0; j < 4; ++j)
#pragma unroll
      for (int r = 0; r < 4; ++r)
        T[(wm * 64 + i * 16 + lq * 4 + r) * 136 + wn * 64 + j * 16 + lm] =
            f2bf(acc[i][j][r]);
  __syncthreads();

#pragma unroll
  for (int it = 0; it < 8; ++it) {
    int item = tid + it * 256;  // 0..2047
    int L = item & 63, nb = (item >> 6) & 7, cc2 = item >> 9;
    int co = nb * 16 + (L & 15);
    int c0 = cc2 * 32 + (L >> 4) * 8;
    *reinterpret_cast<uint4*>(
        Wf1 + (size_t)b * 147456 +
        ((size_t)(((tap * 4 + cc2) * 8 + nb) * 64 + L)) * 8) =
        *reinterpret_cast<const uint4*>(T + co * 136 + c0);
  }
}

extern "C" void kernel_launch(void* const* d_in, const int* in_sizes, int n_in,
                              void* d_out, int out_size, void* d_ws, size_t ws_size,
                              hipStream_t stream) {
  const float* F_in = (const float*)d_in[0];
  const float* Pspe = (const float*)d_in[1];
  const float* q_w = (const float*)d_in[2];
  const float* q_b = (const float*)d_in[3];
  const float* k_w = (const float*)d_in[4];
  const float* k_b = (const float*)d_in[5];
  const float* v_w = (const float*)d_in[6];
  const float* v_b = (const float*)d_in[7];
  const float* f1_w = (const float*)d_in[8];
  const float* f1_b = (const float*)d_in[9];
  const float* f2_w = (const float*)d_in[10];
  const float* f2_b = (const float*)d_in[11];
  float* out = (float*)d_out;

  char* ws = (char*)d_ws;
  const size_t SZ = 16777216;  // 65536*128*2 bytes
  u16* X = (u16*)(ws);                   // NHWC bf16 input; SP aliases later
  u16* QP = (u16*)(ws + SZ);             // packed Q; later Hid
  u16* KP = (u16*)(ws + 2 * SZ);         // packed K
  u16* V = (u16*)(ws + 3 * SZ);          // natural V (alive until f2')
  u16* Wpk = (u16*)(ws + 4 * SZ);                    // 1,474,560 B
  u16* Mpk = (u16*)(ws + 4 * SZ + 1474560);          // 524,288 B
  u16* Mpk2 = (u16*)(ws + 4 * SZ + 1998848);         // 524,288 B
  u16* Wf1 = (u16*)(ws + 4 * SZ + 2523136);          // 4,718,592 B -> ~74.4 MB
  float* SP = (float*)ws;                // 8.39 MB partials — aliases X (dead)
  u16* Hid = QP;                         // f1' output — aliases QP (dead)

  pack_xw<<<1384, 256, 0, stream>>>(F_in, X, q_w, k_w, v_w, f1_w, f2_w, Wpk);
  conv_qkv<<<1024, 256, 0, stream>>>(X, Wpk, q_b, k_b, v_b, QP, KP, V);
  attn_s<<<128, 256, 0, stream>>>(QP, KP, SP);
  attn_rm<<<16, 256, 0, stream>>>(SP, Pspe, Mpk, Mpk2);
  wfold1<<<144, 256, 0, stream>>>(Wpk + 3 * 147456, Mpk2, Wf1);
  conv_gemm<1><<<512, 256, 0, stream>>>(V, Wf1, f1_b, Hid, nullptr, nullptr,
                                        nullptr);
  conv_gemm<3><<<512, 256, 0, stream>>>(Hid, Wpk + 4 * 147456, f2_b, nullptr,
                                        out, V, Mpk);
}